// Round 12
// baseline (137.039 us; speedup 1.0000x reference)
//
#include <hip/hip_runtime.h>
#include <math.h>

typedef unsigned int uint;
typedef unsigned short ushort;
typedef unsigned char uchar;
typedef unsigned long ulong_;
typedef __attribute__((ext_vector_type(4))) float f32x4;
typedef __attribute__((ext_vector_type(2))) unsigned long ulongx2;

// Problem constants
#define BB  16384
#define DD  64
#define NT_ 128
#define NZ_ 2048
#define NJ_ 2049   // NZ+1

// workspace layout (float offsets) — all regions disjoint (R6 lesson: verify
// end offsets; byte-sized tables: floats = bytes/4).
#define BIAS_OFF 0         // fp32 [64]                         -> end 64
#define IL2_OFF  64        // il2[c] = exp(-2 lsz)*log2e [2048]   -> end 2112
#define A0_OFF   2112      // a0[c]  = -cc * il2          [2048]  -> end 4160
#define NIQ_OFF  4160      // niq[c] = -inv * q           [2048]  -> end 6208
#define CZP_OFF  6208      // fp8 cz paired [NZ][64]B = 32768 fl  -> end 38976
#define WZP_OFF  38976     // fp8 inv*Wz paired [NZ][64]B = 32768 -> end 71744
#define WZBP_OFF 71744     // fp8 Wz packed [64][64][32]B = 32768 -> end 104512
#define PART_OFF 104512    // fp32 partials [4][64][NJ_] = 524544 -> end 629056
// end 629056 floats ~= 2.52 MB

// ---------------- fp8 e4m3 (OCP) conversion helpers ----------------
#if __has_builtin(__builtin_amdgcn_cvt_pk_fp8_f32)
__device__ __forceinline__ uint pk4_fp8(float a, float b, float c, float d) {
  int v = __builtin_amdgcn_cvt_pk_fp8_f32(a, b, 0, false);
  v = __builtin_amdgcn_cvt_pk_fp8_f32(c, d, v, true);
  return (uint)v;
}
__device__ __forceinline__ uchar f8_1(float x) {
  return (uchar)(__builtin_amdgcn_cvt_pk_fp8_f32(x, x, 0, false) & 0xFF);
}
#else
__device__ __forceinline__ uint sw_f8(float x) {
  uint u = __float_as_uint(x);
  uint s = (u >> 24) & 0x80u;
  float ax = __uint_as_float(u & 0x7FFFFFFFu);
  if (!(ax >= 0.015625f)) return s;          // flush tiny / NaN -> signed zero
  if (ax >= 448.f) return s | 0x7Eu;
  uint q = __float_as_uint(ax);
  q += 0x7FFFFu + ((q >> 20) & 1u);          // RNE at mantissa bit 20
  uint e = (q >> 23) - 120u;                 // rebias (127 -> 7)
  return s | ((e & 0xFu) << 3) | ((q >> 20) & 7u);
}
__device__ __forceinline__ uchar f8_1(float x) { return (uchar)sw_f8(x); }
__device__ __forceinline__ uint pk4_fp8(float a, float b, float c, float d) {
  return sw_f8(a) | (sw_f8(b) << 8) | (sw_f8(c) << 16) | (sw_f8(d) << 24);
}
#endif

// ---------------------------------------------------------------------------
// Kernel 1 (stage 1): split-K partial sums of W_t = einsum('dij,i->dj').
// 2304 blocks (9/CU, 32 waves/CU) -> latency-tolerant W read (67 MB, BW-bound,
// ~5.2 TB/s, near the 10.6us floor). R2: fewer waves/CU collapses to 330 GB/s.
__global__ __launch_bounds__(256) void k_wt1(
    const float* __restrict__ t, const float* __restrict__ ct,
    const float* __restrict__ lst, const float* __restrict__ W,
    float* __restrict__ part)   // [4][64][NJ_]
{
  __shared__ float ph[32];
  int tx = threadIdx.x;
  int d  = blockIdx.y;
  int ic = blockIdx.z;
  if (tx < 32) {
    int i = ic * 32 + tx;
    float r = fabsf(t[0] - ct[i]) * __expf(-lst[i]);
    ph[tx] = __expf(-r * r);
  }
  __syncthreads();
  int j = blockIdx.x * 256 + tx;
  if (j >= NJ_) return;
  const float* Wp = W + (size_t)d * NT_ * NJ_ + (size_t)(ic * 32) * NJ_ + j;
  float acc = 0.f;
#pragma unroll
  for (int k = 0; k < 32; ++k) acc += Wp[(size_t)k * NJ_] * ph[k];
  part[((size_t)ic * 64 + d) * NJ_ + j] = acc;
}

// ---------------------------------------------------------------------------
// Kernel 2 (stage 2): 256 blocks x 256 thr, 8 centres/block.
// Emits PAIRED k-half tables (R11): czp[c][64]B = {k0 16B | k1 16B} per 8-k
// group -> one dwordx4 feeds both k-half MFMA fragments. wzp pre-scaled by
// inv (bit-identical here since lsz==0 -> inv==1). Planar consts {il2,a0,niq}.
__global__ __launch_bounds__(256) void k_prep2(
    const float* __restrict__ part, const float* __restrict__ cz,
    const float* __restrict__ lsz,
    float* __restrict__ bias,
    float* __restrict__ il2a, float* __restrict__ a0a, float* __restrict__ niqa,
    uchar* __restrict__ czp, uchar* __restrict__ wzp,
    uchar* __restrict__ wzbp8)
{
  __shared__ float wt[64][9];   // [d][c_local]
  int tid = threadIdx.x;
  int cb0 = blockIdx.x * 8;
#pragma unroll
  for (int h = 0; h < 2; ++h) {
    int f = h * 256 + tid;      // 512 = 64 d x 8 c
    int d = f >> 3, c = f & 7;
    size_t idx = (size_t)d * NJ_ + cb0 + c;
    float s = part[idx] + part[(size_t)64 * NJ_ + idx]
            + part[(size_t)128 * NJ_ + idx] + part[(size_t)192 * NJ_ + idx];
    wt[d][c] = s;
    int cg = cb0 + c;
    wzbp8[((size_t)(cg >> 5) * 64 + d) * 32 + (cg & 31)] = f8_1(s);
  }
  if (blockIdx.x == 0 && tid < 64) {
    size_t idx = (size_t)tid * NJ_ + 2048;
    bias[tid] = part[idx] + part[(size_t)64 * NJ_ + idx]
              + part[(size_t)128 * NJ_ + idx] + part[(size_t)192 * NJ_ + idx];
  }
  __syncthreads();
  int cl = tid >> 5;            // centre within block 0..7
  int k  = tid & 31;            // 0..31
  int c  = cb0 + cl;
  float inv = __expf(-2.f * lsz[c]);
  float cv0 = cz[(size_t)c * DD + k];
  float cv1 = cz[(size_t)c * DD + 32 + k];
  // paired layout: [c][ (k>>3)*16 + (k&7) ] = k0 half, +8 = k1 half
  size_t pbase = (size_t)c * 64 + ((k >> 3) << 4) + (k & 7);
  czp[pbase]     = f8_1(cv0);
  czp[pbase + 8] = f8_1(cv1);
  float w0 = wt[k][cl], w1 = wt[32 + k][cl];
  wzp[pbase]     = f8_1(w0 * inv);
  wzp[pbase + 8] = f8_1(w1 * inv);
  float ca = cv0 * cv0 + cv1 * cv1;
  float qa = w0 * cv0 + w1 * cv1;   // q uses exact (unscaled) Wz
  qa += __shfl_xor(qa, 1);  ca += __shfl_xor(ca, 1);
  qa += __shfl_xor(qa, 2);  ca += __shfl_xor(ca, 2);
  qa += __shfl_xor(qa, 4);  ca += __shfl_xor(ca, 4);
  qa += __shfl_xor(qa, 8);  ca += __shfl_xor(ca, 8);
  qa += __shfl_xor(qa, 16); ca += __shfl_xor(ca, 16);
  if (k == 0) {
    float il2 = inv * 1.44269504f;     // inv * log2e
    il2a[c] = il2;
    a0a[c]  = -ca * il2;               // -cc * il2
    niqa[c] = -inv * qa;               // -inv * q
  }
}

// ---------------------------------------------------------------------------
// Main fused MFMA kernel — R12: R11 base (best measured, 136.4 total) + the
// per-chunk CONSTS moved into the double-buffered prefetch.
// R11's consts (ilv/a0v/nqv, 6 float4/chunk) were issued at chunk top and
// consumed right after GEMM1 — only ~120 cyc of MFMA cover vs ~250 cyc L2
// latency -> ~150+ cyc exposed per chunk. (This was a silent regression in
// the R6 planar split: R5's packed Asc WAS dbuf'd.) Restoring the dbuf costs
// +24 VGPR (~190 total) — same (256,2)/BM=32 regime that has kept register
// prefetch live in every round it was used (R2/R5/R7/R11). Everything else
// is bit-identical to R11.
__global__ __launch_bounds__(256, 2) void k_fused(
    const float* __restrict__ z,
    const uchar* __restrict__ czp, const uchar* __restrict__ wzp,
    const uchar* __restrict__ wzbp8,
    const float* __restrict__ il2a, const float* __restrict__ a0a,
    const float* __restrict__ niqa,
    const float* __restrict__ bias, float* __restrict__ out)
{
  __shared__ float eps[32 * 68];   // dz combine scratch (only LDS use)
  __shared__ float dlr[4][32];

  int tid  = threadIdx.x;
  int ws   = tid >> 6;           // wave = c-split group 0..3
  int lane = tid & 63;
  int lrow = lane & 15, quad = lane >> 4;
  int b0 = blockIdx.x * 32;

  // ---- prologue: read fp32 z rows, pack fp8 frags + own-row norms ----
  long az[2][2];
  float nzz[2];
#pragma unroll
  for (int mt = 0; mt < 2; ++mt) {
    const float* zr = z + (size_t)(b0 + mt * 16 + lrow) * DD + quad * 8;
    float4 v0 = *(const float4*)zr;
    float4 v1 = *(const float4*)(zr + 4);
    float4 v2 = *(const float4*)(zr + 32);
    float4 v3 = *(const float4*)(zr + 36);
    uint l0 = pk4_fp8(v0.x, v0.y, v0.z, v0.w);
    uint l1 = pk4_fp8(v1.x, v1.y, v1.z, v1.w);
    uint h0 = pk4_fp8(v2.x, v2.y, v2.z, v2.w);
    uint h1 = pk4_fp8(v3.x, v3.y, v3.z, v3.w);
    az[mt][0] = (long)(((ulong_)l1 << 32) | l0);
    az[mt][1] = (long)(((ulong_)h1 << 32) | h0);
    float ss = v0.x * v0.x + v0.y * v0.y + v0.z * v0.z + v0.w * v0.w
             + v1.x * v1.x + v1.y * v1.y + v1.z * v1.z + v1.w * v1.w
             + v2.x * v2.x + v2.y * v2.y + v2.z * v2.z + v2.w * v2.w
             + v3.x * v3.x + v3.y * v3.y + v3.z * v3.z + v3.w * v3.w;
    ss += __shfl_xor(ss, 16);    // combine the 4 quad partials -> full row sum
    ss += __shfl_xor(ss, 32);
    nzz[mt] = -ss;               // own row's -|z|^2
  }

  f32x4 acc[2][4];
#pragma unroll
  for (int mt = 0; mt < 2; ++mt)
#pragma unroll
    for (int nt = 0; nt < 4; ++nt) acc[mt][nt] = (f32x4){0.f, 0.f, 0.f, 0.f};
  float dl[2] = {0.f, 0.f};

  const f32x4 zero = (f32x4){0.f, 0.f, 0.f, 0.f};
  int cbase = ws * 512;

  // ---- register double-buffered prefetch state (frags + consts) ----
  long Abc0[2][2], Abc1[2][2], Abw0[2][2], Abw1[2][2], Abb[2][4];
  float4 Ail[2][2], Aa0[2][2], Anq[2][2];
#define LOADB(PAR, C0)                                                         \
  do {                                                                         \
    int c0_ = (C0);                                                            \
    _Pragma("unroll")                                                          \
    for (int nt = 0; nt < 2; ++nt) {                                           \
      int cg_ = c0_ + nt * 16 + lrow;                                          \
      size_t po_ = (size_t)cg_ * 64 + quad * 16;                               \
      ulongx2 va_ = *(const ulongx2*)(czp + po_);                              \
      ulongx2 vw_ = *(const ulongx2*)(wzp + po_);                              \
      Abc0[PAR][nt] = (long)va_.x;                                             \
      Abc1[PAR][nt] = (long)va_.y;                                             \
      Abw0[PAR][nt] = (long)vw_.x;                                             \
      Abw1[PAR][nt] = (long)vw_.y;                                             \
      int cb_ = c0_ + nt * 16 + quad * 4;                                      \
      Ail[PAR][nt] = *(const float4*)&il2a[cb_];                               \
      Aa0[PAR][nt] = *(const float4*)&a0a[cb_];                                \
      Anq[PAR][nt] = *(const float4*)&niqa[cb_];                               \
    }                                                                          \
    size_t cb2_ = (size_t)(c0_ >> 5) * 64 * 32;                                \
    _Pragma("unroll")                                                          \
    for (int nt = 0; nt < 4; ++nt)                                             \
      Abb[PAR][nt] =                                                           \
          *(const long*)(wzbp8 + cb2_ + (size_t)(nt * 16 + lrow) * 32 + quad * 8); \
  } while (0)

  LOADB(0, cbase);
#pragma unroll 2
  for (int it = 0; it < 16; ++it) {
    int par = it & 1;

    // ---- GEMM1 (swapped): D[c_local][r_local]; thread owns row lrow ----
    f32x4 d1a[2][2], d2a[2][2];
#pragma unroll
    for (int nt = 0; nt < 2; ++nt)
#pragma unroll
      for (int mt = 0; mt < 2; ++mt) {
        f32x4 d1 = __builtin_amdgcn_mfma_f32_16x16x32_fp8_fp8(Abc0[par][nt], az[mt][0], zero, 0, 0, 0);
        d1       = __builtin_amdgcn_mfma_f32_16x16x32_fp8_fp8(Abc1[par][nt], az[mt][1], d1,   0, 0, 0);
        f32x4 d2 = __builtin_amdgcn_mfma_f32_16x16x32_fp8_fp8(Abw0[par][nt], az[mt][0], zero, 0, 0, 0);
        d2       = __builtin_amdgcn_mfma_f32_16x16x32_fp8_fp8(Abw1[par][nt], az[mt][1], d2,   0, 0, 0);
        d1a[nt][mt] = d1;
        d2a[nt][mt] = d2;
      }

    // ---- prefetch next chunk (frags + consts): elementwise covers L2 ----
    LOADB(par ^ 1, cbase + ((it + 1) & 15) * 32);

    // ---- elementwise (6 ops/elem): p = exp2(clamped), dl accum, pack ----
    // element (mt,nt,i): r = b0+mt*16+lrow, c = c0+nt*16+quad*4+i
    uint u00, u01, u10, u11;
#pragma unroll
    for (int mt = 0; mt < 2; ++mt)
#pragma unroll
      for (int nt = 0; nt < 2; ++nt) {
        float pv[4];
#pragma unroll
        for (int i = 0; i < 4; ++i) {
          float tt = fmaf(d1a[nt][mt][i], 2.f, nzz[mt]);     // 2 d1 - zz
          float e  = fmaf(Ail[par][nt][i], tt, Aa0[par][nt][i]); // il2*(2d1-zz-cc)
          e = fminf(e, 0.f);
          float p;
          asm("v_exp_f32 %0, %1" : "=v"(p) : "v"(e));        // exp2
          float g = d2a[nt][mt][i] + Anq[par][nt][i];        // inv*(z.Wz - q)
          dl[mt] = fmaf(p, g, dl[mt]);
          pv[i] = p;
        }
        uint uv = pk4_fp8(pv[0], pv[1], pv[2], pv[3]);
        if (mt == 0) { if (nt == 0) u00 = uv; else u01 = uv; }
        else         { if (nt == 0) u10 = uv; else u11 = uv; }
      }

    // ---- in-wave transpose: phi (own-row layout) -> GEMM2 A-fragments ----
    int  sl = lrow + ((lane & 16) << 1);   // lrow + 32*(t&1)
    bool hh = lane >= 32;                  // nt = t>>1
    uint l0a = __shfl(u00, sl),      l1a = __shfl(u01, sl);
    uint h0a = __shfl(u00, sl + 16), h1a = __shfl(u01, sl + 16);
    uint lo0 = hh ? l1a : l0a,       hi0 = hh ? h1a : h0a;
    long ap0 = (long)(((ulong_)hi0 << 32) | lo0);
    uint l0b = __shfl(u10, sl),      l1b = __shfl(u11, sl);
    uint h0b = __shfl(u10, sl + 16), h1b = __shfl(u11, sl + 16);
    uint lo1 = hh ? l1b : l0b,       hi1 = hh ? h1b : h0b;
    long ap1 = (long)(((ulong_)hi1 << 32) | lo1);

    // ---- GEMM2: dz += phi @ Wz ----
    __builtin_amdgcn_s_setprio(1);
#pragma unroll
    for (int nt = 0; nt < 4; ++nt) {
      acc[0][nt] = __builtin_amdgcn_mfma_f32_16x16x32_fp8_fp8(ap0, Abb[par][nt], acc[0][nt], 0, 0, 0);
      acc[1][nt] = __builtin_amdgcn_mfma_f32_16x16x32_fp8_fp8(ap1, Abb[par][nt], acc[1][nt], 0, 0, 0);
    }
    __builtin_amdgcn_s_setprio(0);
  }
#undef LOADB

  // ---- dl partials: sum over the 4 quads holding the same row ----
#pragma unroll
  for (int mt = 0; mt < 2; ++mt) {
    float v = dl[mt];
    v += __shfl_xor(v, 16);
    v += __shfl_xor(v, 32);
    if (quad == 0) dlr[ws][mt * 16 + lrow] = v;
  }

  // ---- dz combine across the 4 c-split waves ----
  for (int s = 0; s < 4; ++s) {
    __syncthreads();
    if (ws == s) {
#pragma unroll
      for (int mt = 0; mt < 2; ++mt)
#pragma unroll
        for (int nt = 0; nt < 4; ++nt)
#pragma unroll
          for (int i = 0; i < 4; ++i) {
            int r = mt * 16 + quad * 4 + i;
            int d = nt * 16 + lrow;
            if (s == 0) eps[r * 68 + d] = acc[mt][nt][i];
            else        eps[r * 68 + d] += acc[mt][nt][i];
          }
    }
  }
  __syncthreads();

  // ---- outputs ----
  {
    int r = tid >> 3, d0 = (tid & 7) * 8;   // 256 thr x 8 floats = 32x64
    float4 e0 = *(const float4*)&eps[r * 68 + d0];
    float4 e1 = *(const float4*)&eps[r * 68 + d0 + 4];
    float4 bv0 = *(const float4*)&bias[d0];
    float4 bv1 = *(const float4*)&bias[d0 + 4];
    float4 o0, o1;
    o0.x = e0.x + bv0.x; o0.y = e0.y + bv0.y; o0.z = e0.z + bv0.z; o0.w = e0.w + bv0.w;
    o1.x = e1.x + bv1.x; o1.y = e1.y + bv1.y; o1.z = e1.z + bv1.z; o1.w = e1.w + bv1.w;
    *(float4*)&out[(size_t)(b0 + r) * DD + d0]     = o0;
    *(float4*)&out[(size_t)(b0 + r) * DD + d0 + 4] = o1;
  }
  if (tid < 32) {
    float s = dlr[0][tid] + dlr[1][tid] + dlr[2][tid] + dlr[3][tid];
    out[(size_t)BB * DD + b0 + tid] = 2.f * s;
  }
}

// ---------------------------------------------------------------------------
extern "C" void kernel_launch(void* const* d_in, const int* in_sizes, int n_in,
                              void* d_out, int out_size, void* d_ws, size_t ws_size,
                              hipStream_t stream)
{
  const float* t   = (const float*)d_in[0];
  const float* z   = (const float*)d_in[1];
  // d_in[2] = logp_z (unused)
  const float* cz  = (const float*)d_in[3];
  const float* lsz = (const float*)d_in[4];
  const float* ct  = (const float*)d_in[5];
  const float* lst = (const float*)d_in[6];
  const float* W   = (const float*)d_in[7];
  float* out = (float*)d_out;
  float* ws  = (float*)d_ws;

  float*  bias = ws + BIAS_OFF;
  float*  il2a = ws + IL2_OFF;
  float*  a0a  = ws + A0_OFF;
  float*  niqa = ws + NIQ_OFF;
  uchar*  czp  = (uchar*)(ws + CZP_OFF);
  uchar*  wzp  = (uchar*)(ws + WZP_OFF);
  uchar*  wzbp8 = (uchar*)(ws + WZBP_OFF);
  float*  part = ws + PART_OFF;

  k_wt1<<<dim3(9, 64, 4), 256, 0, stream>>>(t, ct, lst, W, part);
  k_prep2<<<dim3(256), 256, 0, stream>>>(part, cz, lsz, bias,
                                         il2a, a0a, niqa,
                                         czp, wzp, wzbp8);
  k_fused<<<dim3(BB / 32), 256, 0, stream>>>(z, czp, wzp, wzbp8,
                                             il2a, a0a, niqa, bias, out);
}